// Round 8
// baseline (114.785 us; speedup 1.0000x reference)
//
#include <hip/hip_runtime.h>
#include <hip/hip_bf16.h>
#include <stdint.h>

#define M_DIM 2048
#define N_DIM 4096
#define K_DIM 4096
#define BK 64

typedef __bf16 bf16x8 __attribute__((ext_vector_type(8)));
typedef float f32x4 __attribute__((ext_vector_type(4)));
typedef unsigned short ushort8_t __attribute__((ext_vector_type(8)));

__device__ __forceinline__ unsigned short f32_to_bf16_rne(float f) {
    union { float f; uint32_t u; } cvt;
    cvt.f = f;
    uint32_t u = cvt.u;
    uint32_t r = (u + 0x7fffu + ((u >> 16) & 1u)) >> 16;
    return (unsigned short)r;
}

__device__ __forceinline__ void gload_lds16(const void* g, void* l) {
    __builtin_amdgcn_global_load_lds(
        (__attribute__((address_space(1))) const void*)g,
        (__attribute__((address_space(3))) void*)l,
        16, 0, 0);
}

// ---------------------------------------------------------------------------
__global__ void convert_x_kernel(const float* __restrict__ x,
                                 unsigned short* __restrict__ xb, int n8) {
    int i = blockIdx.x * blockDim.x + threadIdx.x;
    int stride = gridDim.x * blockDim.x;
    for (; i < n8; i += stride) {
        const float4* p = (const float4*)(x + (size_t)i * 8);
        float4 v0 = p[0];
        float4 v1 = p[1];
        ushort8_t o;
        o[0] = f32_to_bf16_rne(v0.x);
        o[1] = f32_to_bf16_rne(v0.y);
        o[2] = f32_to_bf16_rne(v0.z);
        o[3] = f32_to_bf16_rne(v0.w);
        o[4] = f32_to_bf16_rne(v1.x);
        o[5] = f32_to_bf16_rne(v1.y);
        o[6] = f32_to_bf16_rne(v1.z);
        o[7] = f32_to_bf16_rne(v1.w);
        *(ushort8_t*)(xb + (size_t)i * 8) = o;
    }
}

// ---------------------------------------------------------------------------
__global__ void transpose_convert_w(const float* __restrict__ W,
                                    unsigned short* __restrict__ Wt) {
    __shared__ float tile[64][65];
    const int k0 = blockIdx.y * 64;
    const int n0 = blockIdx.x * 64;
    const int t  = threadIdx.x;
    const int tx = t & 15;
    const int ty = t >> 4;

#pragma unroll
    for (int r = 0; r < 4; ++r) {
        int row = ty + 16 * r;
        float4 v = *(const float4*)(W + (size_t)(k0 + row) * N_DIM + n0 + tx * 4);
        tile[row][tx * 4 + 0] = v.x;
        tile[row][tx * 4 + 1] = v.y;
        tile[row][tx * 4 + 2] = v.z;
        tile[row][tx * 4 + 3] = v.w;
    }
    __syncthreads();
#pragma unroll
    for (int r = 0; r < 4; ++r) {
        int nrow = ty + 16 * r;
        ushort4 o;
        o.x = f32_to_bf16_rne(tile[tx * 4 + 0][nrow]);
        o.y = f32_to_bf16_rne(tile[tx * 4 + 1][nrow]);
        o.z = f32_to_bf16_rne(tile[tx * 4 + 2][nrow]);
        o.w = f32_to_bf16_rne(tile[tx * 4 + 3][nrow]);
        *(ushort4*)(Wt + (size_t)(n0 + nrow) * K_DIM + k0 + tx * 4) = o;
    }
}

// ---------------------------------------------------------------------------
// Split-K GEMM, 256x256 WG tile, 8 waves of 128x64 (MFMA-dominant geometry:
// per K-tile per CU LDS reads 2260 cyc < MFMA 2484 cyc). Double-buffered
// 128 KiB LDS, R3's proven 0-conflict 128B-row swizzle. 2 phases per K-tile
// split by mi-half so A-units per phase have disjoint parity:
//   P0 (mi0..3): uses A-units {0,2} + B all  -> staged as batch0 (6 gloads)
//   P1 (mi4..7): uses A-units {1,3}          -> staged as batch1 (2 gloads)
// Stage batches for tile tau+1 during tau; counted waits (never 0):
//   mid-tile:  vmcnt(6)  (drains batch1 of tau,  issued 1 phase ago)
//   tile-end:  lgkmcnt(0) + vmcnt(2) (drains batch0 of tau+1; WAR for next
//              P0's staging into the buffer this tile was reading)
// ks=0 WGs write out (+bias); ks=1 write f32 partial; reduce_add combines.
// ---------------------------------------------------------------------------
__global__ __launch_bounds__(512, 2) void gemm_bf16_256(
    const unsigned short* __restrict__ A,
    const unsigned short* __restrict__ Bt,
    const float* __restrict__ bias,
    float* __restrict__ out,
    float* __restrict__ p1) {
    __shared__ unsigned short sA[2][256 * BK];  // 2 x 32 KiB
    __shared__ unsigned short sB[2][256 * BK];  // 2 x 32 KiB

    const int t    = threadIdx.x;
    const int lane = t & 63;
    const int wave = t >> 6;
    const int wm   = wave >> 2;  // 0..1
    const int wn   = wave & 3;   // 0..3
    const int lrow = lane & 15;
    const int lhi  = lane >> 4;

    // T1: XCD swizzle (256 WGs, bijective); each XCD owns contiguous swz chunk
    const int wg  = blockIdx.x;
    const int swz = (wg & 7) * 32 + (wg >> 3);
    const int ks  = swz >> 7;        // 0..1 : K-half
    const int rem = swz & 127;
    const int m0  = (rem >> 4) * 256;
    const int n0  = (rem & 15) * 256;
    const int k0  = ks * 2048;

    // staging: per-thread element index (inverse-swizzled global source)
    const int rowc = t >> 3;                 // 0..63
    const int lc   = (t & 7) ^ (rowc & 7);   // swizzled k-slot
    const int idxA = (m0 + rowc) * K_DIM + lc * 8 + k0;
    const int idxB = (n0 + rowc) * K_DIM + lc * 8 + k0;
    const int dst  = t * 16;

    auto stage0 = [&](int buf, int ko) {  // A-units 0,2 + B-units 0..3
        char* bA = (char*)sA[buf];
        char* bB = (char*)sB[buf];
        gload_lds16(A  + idxA + 0 * 64 * K_DIM + ko, bA + 0 * 8192 + dst);
        gload_lds16(A  + idxA + 2 * 64 * K_DIM + ko, bA + 2 * 8192 + dst);
        gload_lds16(Bt + idxB + 0 * 64 * K_DIM + ko, bB + 0 * 8192 + dst);
        gload_lds16(Bt + idxB + 1 * 64 * K_DIM + ko, bB + 1 * 8192 + dst);
        gload_lds16(Bt + idxB + 2 * 64 * K_DIM + ko, bB + 2 * 8192 + dst);
        gload_lds16(Bt + idxB + 3 * 64 * K_DIM + ko, bB + 3 * 8192 + dst);
    };
    auto stage1 = [&](int buf, int ko) {  // A-units 1,3
        char* bA = (char*)sA[buf];
        gload_lds16(A + idxA + 1 * 64 * K_DIM + ko, bA + 1 * 8192 + dst);
        gload_lds16(A + idxA + 3 * 64 * K_DIM + ko, bA + 3 * 8192 + dst);
    };

    f32x4 acc[8][4];
#pragma unroll
    for (int i = 0; i < 8; ++i)
#pragma unroll
        for (int j = 0; j < 4; ++j) acc[i][j] = (f32x4)0.0f;

    const int NT = 2048 / BK;  // 32

    // fragment offsets (row&7 == lrow&7; proven 0-conflict pattern)
    const int rowOffA = (wm * 128 + lrow) * 128;  // bytes; + mi*2048
    const int rowOffB = (wn * 64 + lrow) * 128;   // bytes; + nj*2048
    const int s0 = ((0 + lhi) ^ (lrow & 7)) * 16;  // kk=0 slot bytes
    const int s1 = ((4 + lhi) ^ (lrow & 7)) * 16;  // kk=1 slot bytes

    // prologue: tile 0 fully staged; publish batch0, keep batch1 in flight
    stage0(0, 0);
    stage1(0, 0);
    asm volatile("s_waitcnt vmcnt(2)" ::: "memory");
    __builtin_amdgcn_s_barrier();
    __builtin_amdgcn_sched_barrier(0);

#pragma unroll 2
    for (int tau = 0; tau < NT; ++tau) {
        const int buf = tau & 1;
        const int nb  = buf ^ 1;
        const int ko  = ((tau + 1 < NT) ? tau + 1 : NT - 1) * BK;
        const char* bA = (const char*)sA[buf];
        const char* bB = (const char*)sB[buf];

        bf16x8 bf0[4], bf1[4];

        // ================= P0: mi 0..3 (A-units {0,2}, B all) =============
        {
            stage0(nb, ko);
            bf16x8 af0[4], af1[4];
#pragma unroll
            for (int mi = 0; mi < 4; ++mi) {
                af0[mi] = *(const bf16x8*)(bA + rowOffA + mi * 2048 + s0);
                af1[mi] = *(const bf16x8*)(bA + rowOffA + mi * 2048 + s1);
            }
#pragma unroll
            for (int nj = 0; nj < 4; ++nj) {
                bf0[nj] = *(const bf16x8*)(bB + rowOffB + nj * 2048 + s0);
                bf1[nj] = *(const bf16x8*)(bB + rowOffB + nj * 2048 + s1);
            }
            __builtin_amdgcn_s_setprio(1);
#pragma unroll
            for (int mi = 0; mi < 4; ++mi)
#pragma unroll
                for (int nj = 0; nj < 4; ++nj) {
                    acc[mi][nj] = __builtin_amdgcn_mfma_f32_16x16x32_bf16(
                        af0[mi], bf0[nj], acc[mi][nj], 0, 0, 0);
                    acc[mi][nj] = __builtin_amdgcn_mfma_f32_16x16x32_bf16(
                        af1[mi], bf1[nj], acc[mi][nj], 0, 0, 0);
                }
            __builtin_amdgcn_s_setprio(0);
        }

        // mid-tile: publish batch1(tau) = A-units {1,3}; never drains to 0
        asm volatile("s_waitcnt vmcnt(6)" ::: "memory");
        __builtin_amdgcn_s_barrier();
        __builtin_amdgcn_sched_barrier(0);

        // ================= P1: mi 4..7 (A-units {1,3}) ====================
        {
            stage1(nb, ko);
            bf16x8 ag0[4], ag1[4];
#pragma unroll
            for (int mi = 0; mi < 4; ++mi) {
                ag0[mi] = *(const bf16x8*)(bA + rowOffA + (mi + 4) * 2048 + s0);
                ag1[mi] = *(const bf16x8*)(bA + rowOffA + (mi + 4) * 2048 + s1);
            }
            __builtin_amdgcn_s_setprio(1);
#pragma unroll
            for (int mi = 0; mi < 4; ++mi)
#pragma unroll
                for (int nj = 0; nj < 4; ++nj) {
                    acc[mi + 4][nj] = __builtin_amdgcn_mfma_f32_16x16x32_bf16(
                        ag0[mi], bf0[nj], acc[mi + 4][nj], 0, 0, 0);
                    acc[mi + 4][nj] = __builtin_amdgcn_mfma_f32_16x16x32_bf16(
                        ag1[mi], bf1[nj], acc[mi + 4][nj], 0, 0, 0);
                }
            __builtin_amdgcn_s_setprio(0);
        }

        // tile-end: WAR (all this tile's LDS reads done) + publish batch0(tau+1)
        asm volatile("s_waitcnt lgkmcnt(0)" ::: "memory");
        asm volatile("s_waitcnt vmcnt(2)" ::: "memory");
        __builtin_amdgcn_s_barrier();
        __builtin_amdgcn_sched_barrier(0);
    }

    // epilogue: C/D layout col=lane&15, row=(lane>>4)*4+reg
    float* dptr = (ks == 0) ? out : p1;
#pragma unroll
    for (int nj = 0; nj < 4; ++nj) {
        int col  = n0 + wn * 64 + nj * 16 + lrow;
        float bv = (ks == 0) ? bias[col] : 0.0f;
#pragma unroll
        for (int mi = 0; mi < 8; ++mi) {
            int rbase = m0 + wm * 128 + mi * 16 + lhi * 4;
#pragma unroll
            for (int r = 0; r < 4; ++r) {
                dptr[(size_t)(rbase + r) * N_DIM + col] = acc[mi][nj][r] + bv;
            }
        }
    }
}

// ---------------------------------------------------------------------------
__global__ void reduce_add(float* __restrict__ out, const float* __restrict__ p1,
                           int n4) {
    int i = blockIdx.x * blockDim.x + threadIdx.x;
    int stride = gridDim.x * blockDim.x;
    for (; i < n4; i += stride) {
        float4 a = ((const float4*)out)[i];
        float4 b = ((const float4*)p1)[i];
        a.x += b.x; a.y += b.y; a.z += b.z; a.w += b.w;
        ((float4*)out)[i] = a;
    }
}

// ---------------------------------------------------------------------------
// Fallback (R3, 72.2us GEMM): used only if ws too small for f32 partials.
// ---------------------------------------------------------------------------
__global__ __launch_bounds__(512, 2) void gemm_bf16_fb(
    const unsigned short* __restrict__ A,
    const unsigned short* __restrict__ Bt,
    const float* __restrict__ bias,
    float* __restrict__ C) {
    __shared__ unsigned short sA[3][128 * BK];
    __shared__ unsigned short sB[3][256 * BK];

    const int t    = threadIdx.x;
    const int lane = t & 63;
    const int wave = t >> 6;
    const int wm   = wave >> 2;
    const int wn   = wave & 3;
    const int lrow = lane & 15;
    const int lhi  = lane >> 4;

    const int wg  = blockIdx.x;
    const int swz = (wg & 7) * 32 + (wg >> 3);
    const int m0  = (swz >> 4) * 128;
    const int n0  = (swz & 15) * 256;

    auto stageA = [&](int buf, int tile, int c) {
        int row = c >> 3, p = c & 7;
        int l   = p ^ (row & 7);
        gload_lds16(A + (size_t)(m0 + row) * K_DIM + tile * BK + l * 8,
                    (char*)sA[buf] + c * 16);
    };
    auto stageB = [&](int buf, int tile, int c) {
        int row = c >> 3, p = c & 7;
        int l   = p ^ (row & 7);
        gload_lds16(Bt + (size_t)(n0 + row) * K_DIM + tile * BK + l * 8,
                    (char*)sB[buf] + c * 16);
    };

    f32x4 acc[4][4];
#pragma unroll
    for (int i = 0; i < 4; ++i)
#pragma unroll
        for (int j = 0; j < 4; ++j) acc[i][j] = (f32x4)0.0f;

    const int NT = K_DIM / BK;

    stageA(0, 0, t); stageA(0, 0, t + 512);
    stageB(0, 0, t); stageB(0, 0, t + 512);
    stageB(0, 0, t + 1024); stageB(0, 0, t + 1536);
    stageA(1, 1, t); stageA(1, 1, t + 512);
    stageB(1, 1, t); stageB(1, 1, t + 512);
    stageB(1, 1, t + 1024); stageB(1, 1, t + 1536);

    const int rowOffA = (wm * 64 + lrow) * 128;
    const int rowOffB = (wn * 64 + lrow) * 128;
    const int s0 = ((0 + lhi) ^ (lrow & 7)) * 16;
    const int s1 = ((4 + lhi) ^ (lrow & 7)) * 16;

    int bufC = 0, bufS = 2;
    for (int tau = 0; tau < NT; ++tau) {
        const int tile2 = (tau + 2 < NT) ? tau + 2 : NT - 1;
        asm volatile("s_waitcnt vmcnt(6) lgkmcnt(0)" ::: "memory");
        __builtin_amdgcn_s_barrier();
        __builtin_amdgcn_sched_barrier(0);
        const char* bA = (const char*)sA[bufC];
        const char* bB = (const char*)sB[bufC];
        {
            bf16x8 af[4], bf[4];
#pragma unroll
            for (int mi = 0; mi < 4; ++mi)
                af[mi] = *(const bf16x8*)(bA + rowOffA + mi * 2048 + s0);
#pragma unroll
            for (int nj = 0; nj < 4; ++nj)
                bf[nj] = *(const bf16x8*)(bB + rowOffB + nj * 2048 + s0);
            stageA(bufS, tile2, t);
            stageA(bufS, tile2, t + 512);
            stageB(bufS, tile2, t);
            __builtin_amdgcn_s_setprio(1);
#pragma unroll
            for (int mi = 0; mi < 4; ++mi)
#pragma unroll
                for (int nj = 0; nj < 4; ++nj)
                    acc[mi][nj] = __builtin_amdgcn_mfma_f32_16x16x32_bf16(
                        af[mi], bf[nj], acc[mi][nj], 0, 0, 0);
            __builtin_amdgcn_s_setprio(0);
        }
        {
            bf16x8 af[4], bf[4];
#pragma unroll
            for (int mi = 0; mi < 4; ++mi)
                af[mi] = *(const bf16x8*)(bA + rowOffA + mi * 2048 + s1);
#pragma unroll
            for (int nj = 0; nj < 4; ++nj)
                bf[nj] = *(const bf16x8*)(bB + rowOffB + nj * 2048 + s1);
            stageB(bufS, tile2, t + 512);
            stageB(bufS, tile2, t + 1024);
            stageB(bufS, tile2, t + 1536);
            __builtin_amdgcn_s_setprio(1);
#pragma unroll
            for (int mi = 0; mi < 4; ++mi)
#pragma unroll
                for (int nj = 0; nj < 4; ++nj)
                    acc[mi][nj] = __builtin_amdgcn_mfma_f32_16x16x32_bf16(
                        af[mi], bf[nj], acc[mi][nj], 0, 0, 0);
            __builtin_amdgcn_s_setprio(0);
        }
        bufC = (bufC == 2) ? 0 : bufC + 1;
        bufS = (bufS == 2) ? 0 : bufS + 1;
    }

#pragma unroll
    for (int nj = 0; nj < 4; ++nj) {
        int col  = n0 + wn * 64 + nj * 16 + lrow;
        float bv = bias[col];
#pragma unroll
        for (int mi = 0; mi < 4; ++mi) {
            int rbase = m0 + wm * 64 + mi * 16 + lhi * 4;
#pragma unroll
            for (int r = 0; r < 4; ++r) {
                C[(size_t)(rbase + r) * N_DIM + col] = acc[mi][nj][r] + bv;
            }
        }
    }
}

// ---------------------------------------------------------------------------
extern "C" void kernel_launch(void* const* d_in, const int* in_sizes, int n_in,
                              void* d_out, int out_size, void* d_ws, size_t ws_size,
                              hipStream_t stream) {
    const float* x    = (const float*)d_in[0];
    const float* w    = (const float*)d_in[1];
    const float* bias = (const float*)d_in[2];
    float* out        = (float*)d_out;

    unsigned short* xb = (unsigned short*)d_ws;                       // 16 MiB
    unsigned short* wt = (unsigned short*)((char*)d_ws + (16u << 20)); // 32 MiB

    convert_x_kernel<<<2048, 256, 0, stream>>>(x, xb, M_DIM * K_DIM / 8);

    dim3 tgrid(N_DIM / 64, K_DIM / 64);
    transpose_convert_w<<<tgrid, 256, 0, stream>>>(w, wt);

    const size_t need = (size_t)(16 + 32 + 32) << 20;  // xb + wt + f32 partial
    if (ws_size >= need) {
        float* p1 = (float*)((char*)d_ws + (48u << 20));
        gemm_bf16_256<<<256, 512, 0, stream>>>(xb, wt, bias, out, p1);
        reduce_add<<<2048, 256, 0, stream>>>(out, p1, M_DIM * N_DIM / 4);
    } else {
        gemm_bf16_fb<<<256, 512, 0, stream>>>(xb, wt, bias, out);
    }
}

// Round 9
// 91.346 us; speedup vs baseline: 1.2566x; 1.2566x over previous
//
#include <hip/hip_runtime.h>
#include <hip/hip_bf16.h>
#include <stdint.h>

#define M_DIM 2048
#define N_DIM 4096
#define K_DIM 4096

#define BM 128
#define BN 256
#define BK 64

typedef __bf16 bf16x8 __attribute__((ext_vector_type(8)));
typedef float f32x4 __attribute__((ext_vector_type(4)));
typedef unsigned short ushort8_t __attribute__((ext_vector_type(8)));

__device__ __forceinline__ unsigned short f32_to_bf16_rne(float f) {
    union { float f; uint32_t u; } cvt;
    cvt.f = f;
    uint32_t u = cvt.u;
    uint32_t r = (u + 0x7fffu + ((u >> 16) & 1u)) >> 16;
    return (unsigned short)r;
}

__device__ __forceinline__ void gload_lds16(const void* g, void* l) {
    __builtin_amdgcn_global_load_lds(
        (__attribute__((address_space(1))) const void*)g,
        (__attribute__((address_space(3))) void*)l,
        16, 0, 0);
}

// ---------------------------------------------------------------------------
__global__ void convert_x_kernel(const float* __restrict__ x,
                                 unsigned short* __restrict__ xb, int n8) {
    int i = blockIdx.x * blockDim.x + threadIdx.x;
    int stride = gridDim.x * blockDim.x;
    for (; i < n8; i += stride) {
        const float4* p = (const float4*)(x + (size_t)i * 8);
        float4 v0 = p[0];
        float4 v1 = p[1];
        ushort8_t o;
        o[0] = f32_to_bf16_rne(v0.x);
        o[1] = f32_to_bf16_rne(v0.y);
        o[2] = f32_to_bf16_rne(v0.z);
        o[3] = f32_to_bf16_rne(v0.w);
        o[4] = f32_to_bf16_rne(v1.x);
        o[5] = f32_to_bf16_rne(v1.y);
        o[6] = f32_to_bf16_rne(v1.z);
        o[7] = f32_to_bf16_rne(v1.w);
        *(ushort8_t*)(xb + (size_t)i * 8) = o;
    }
}

// ---------------------------------------------------------------------------
__global__ void transpose_convert_w(const float* __restrict__ W,
                                    unsigned short* __restrict__ Wt) {
    __shared__ float tile[64][65];
    const int k0 = blockIdx.y * 64;
    const int n0 = blockIdx.x * 64;
    const int t  = threadIdx.x;
    const int tx = t & 15;
    const int ty = t >> 4;

#pragma unroll
    for (int r = 0; r < 4; ++r) {
        int row = ty + 16 * r;
        float4 v = *(const float4*)(W + (size_t)(k0 + row) * N_DIM + n0 + tx * 4);
        tile[row][tx * 4 + 0] = v.x;
        tile[row][tx * 4 + 1] = v.y;
        tile[row][tx * 4 + 2] = v.z;
        tile[row][tx * 4 + 3] = v.w;
    }
    __syncthreads();
#pragma unroll
    for (int r = 0; r < 4; ++r) {
        int nrow = ty + 16 * r;
        ushort4 o;
        o.x = f32_to_bf16_rne(tile[tx * 4 + 0][nrow]);
        o.y = f32_to_bf16_rne(tile[tx * 4 + 1][nrow]);
        o.z = f32_to_bf16_rne(tile[tx * 4 + 2][nrow]);
        o.w = f32_to_bf16_rne(tile[tx * 4 + 3][nrow]);
        *(ushort4*)(Wt + (size_t)(n0 + nrow) * K_DIM + k0 + tx * 4) = o;
    }
}

// ---------------------------------------------------------------------------
// GEMM: C[m][n] = sum_k A[m][k] * Bt[n][k] + bias[n]
// R3 skeleton (triple-buffer, ONE vmcnt(6)+lgkm(0)+barrier per K-tile,
// proven 0-conflict 128B-row swizzle, 16 MFMA clusters with setprio,
// compiler-free regions) with kk-SPLIT WAVE PAIRING:
//   8 waves = 4 regions (64 rows x 128 cols) x 2 kk-roles. Wave (region,kkr)
//   accumulates only its kk-half: reads 4 A + 8 B frags -> 32 MFMA
//   (2.67 MFMA/KB vs R3's 2.0; block LDS reads 128KB -> 96KB per K-tile).
//   Staging bytes/ledger IDENTICAL to R3 (6 gloads/thread/tile, vmcnt(6)).
//   Epilogue: kkr=1 waves dump partials into the (dead) LDS, kkr=0 waves
//   add + write C with bias.
// ---------------------------------------------------------------------------
__global__ __launch_bounds__(512, 2) void gemm_bf16(
    const unsigned short* __restrict__ A,
    const unsigned short* __restrict__ Bt,
    const float* __restrict__ bias,
    float* __restrict__ C) {
    __shared__ __align__(16) char smem[147456];
    // A bufs: smem + buf*16384           (3 x 16 KiB)
    // B bufs: smem + 49152 + buf*32768   (3 x 32 KiB)
    // epilogue partials: smem + region*32768 (4 x 32 KiB, after K-loop)

    const int t      = threadIdx.x;
    const int lane   = t & 63;
    const int wave   = t >> 6;
    const int region = wave >> 1;  // 0..3 : 64x128 output region
    const int kkr    = wave & 1;   // 0/1  : K-half role
    const int rm     = region >> 1;  // 0..1 row block (x64)
    const int rn     = region & 1;   // 0..1 col block (x128)
    const int lrow   = lane & 15;
    const int lhi    = lane >> 4;

    // T1: XCD-aware swizzle (256 WGs, %8==0 -> bijective)
    const int wg  = blockIdx.x;
    const int swz = (wg & 7) * 32 + (wg >> 3);
    const int m0  = (swz >> 4) * BM;
    const int n0  = (swz & 15) * BN;

    // staging: linear LDS dest + inverse-swizzled global source (R3-identical)
    auto stageA = [&](int buf, int tile, int c) {
        int row = c >> 3, p = c & 7;
        int l   = p ^ (row & 7);
        gload_lds16(A + (size_t)(m0 + row) * K_DIM + tile * BK + l * 8,
                    smem + buf * 16384 + c * 16);
    };
    auto stageB = [&](int buf, int tile, int c) {
        int row = c >> 3, p = c & 7;
        int l   = p ^ (row & 7);
        gload_lds16(Bt + (size_t)(n0 + row) * K_DIM + tile * BK + l * 8,
                    smem + 49152 + buf * 32768 + c * 16);
    };

    f32x4 acc[4][8];  // [mi][nj], this wave's kk-half partial
#pragma unroll
    for (int i = 0; i < 4; ++i)
#pragma unroll
        for (int j = 0; j < 8; ++j) acc[i][j] = (f32x4)0.0f;

    const int NT = K_DIM / BK;  // 64

    // prologue: tiles 0 and 1 fully staged (12 chunks/thread in flight)
    stageA(0, 0, t); stageA(0, 0, t + 512);
    stageB(0, 0, t); stageB(0, 0, t + 512);
    stageB(0, 0, t + 1024); stageB(0, 0, t + 1536);
    stageA(1, 1, t); stageA(1, 1, t + 512);
    stageB(1, 1, t); stageB(1, 1, t + 512);
    stageB(1, 1, t + 1024); stageB(1, 1, t + 1536);

    // fragment offsets (row&7 == lrow&7; proven 0-conflict pattern)
    const int rowOffA = (rm * 64 + lrow) * 128;    // + mi*2048, mi 0..3
    const int rowOffB = (rn * 128 + lrow) * 128;   // + nj*2048, nj 0..7
    const int sK = ((kkr * 4 + lhi) ^ (lrow & 7)) * 16;  // this wave's kk slot

    int bufC = 0, bufS = 2;
    for (int tau = 0; tau < NT; ++tau) {
        const int tile2 = (tau + 2 < NT) ? tau + 2 : NT - 1;

        // one wait + one barrier per K-tile; vmcnt NEVER drains to 0
        asm volatile("s_waitcnt vmcnt(6) lgkmcnt(0)" ::: "memory");
        __builtin_amdgcn_s_barrier();
        __builtin_amdgcn_sched_barrier(0);

        const char* bA = smem + bufC * 16384;
        const char* bB = smem + 49152 + bufC * 32768;

        // ---- P0: nj 0..3 ----
        bf16x8 af[4], bf[4];
#pragma unroll
        for (int mi = 0; mi < 4; ++mi)
            af[mi] = *(const bf16x8*)(bA + rowOffA + mi * 2048 + sK);
#pragma unroll
        for (int nj = 0; nj < 4; ++nj)
            bf[nj] = *(const bf16x8*)(bB + rowOffB + nj * 2048 + sK);
        stageA(bufS, tile2, t);
        stageA(bufS, tile2, t + 512);
        stageB(bufS, tile2, t);
        __builtin_amdgcn_s_setprio(1);
#pragma unroll
        for (int mi = 0; mi < 4; ++mi)
#pragma unroll
            for (int nj = 0; nj < 4; ++nj)
                acc[mi][nj] = __builtin_amdgcn_mfma_f32_16x16x32_bf16(
                    af[mi], bf[nj], acc[mi][nj], 0, 0, 0);
        __builtin_amdgcn_s_setprio(0);

        // ---- P1: nj 4..7 ----
        bf16x8 bg[4];
#pragma unroll
        for (int nj = 0; nj < 4; ++nj)
            bg[nj] = *(const bf16x8*)(bB + rowOffB + (nj + 4) * 2048 + sK);
        stageB(bufS, tile2, t + 512);
        stageB(bufS, tile2, t + 1024);
        stageB(bufS, tile2, t + 1536);
        __builtin_amdgcn_s_setprio(1);
#pragma unroll
        for (int mi = 0; mi < 4; ++mi)
#pragma unroll
            for (int nj = 0; nj < 4; ++nj)
                acc[mi][nj + 4] = __builtin_amdgcn_mfma_f32_16x16x32_bf16(
                    af[mi], bg[nj], acc[mi][nj + 4], 0, 0, 0);
        __builtin_amdgcn_s_setprio(0);

        bufC = (bufC == 2) ? 0 : bufC + 1;
        bufS = (bufS == 2) ? 0 : bufS + 1;
    }

    // ---- epilogue: combine kk pair via LDS, then write C + bias ----
    __syncthreads();  // all K-loop LDS reads done; buffers now dead
    if (kkr == 1) {
#pragma unroll
        for (int mi = 0; mi < 4; ++mi)
#pragma unroll
            for (int nj = 0; nj < 8; ++nj)
                *(f32x4*)(smem + region * 32768 +
                          ((mi * 8 + nj) * 64 + lane) * 16) = acc[mi][nj];
    }
    __syncthreads();
    if (kkr == 0) {
        // C/D layout: col=lane&15, row=(lane>>4)*4+reg
#pragma unroll
        for (int nj = 0; nj < 8; ++nj) {
            int col  = n0 + rn * 128 + nj * 16 + lrow;
            float bv = bias[col];
#pragma unroll
            for (int mi = 0; mi < 4; ++mi) {
                f32x4 p = *(const f32x4*)(smem + region * 32768 +
                                          ((mi * 8 + nj) * 64 + lane) * 16);
                int rbase = m0 + rm * 64 + mi * 16 + lhi * 4;
#pragma unroll
                for (int r = 0; r < 4; ++r) {
                    C[(size_t)(rbase + r) * N_DIM + col] =
                        acc[mi][nj][r] + p[r] + bv;
                }
            }
        }
    }
}

// ---------------------------------------------------------------------------
extern "C" void kernel_launch(void* const* d_in, const int* in_sizes, int n_in,
                              void* d_out, int out_size, void* d_ws, size_t ws_size,
                              hipStream_t stream) {
    const float* x    = (const float*)d_in[0];
    const float* w    = (const float*)d_in[1];
    const float* bias = (const float*)d_in[2];
    float* out        = (float*)d_out;

    unsigned short* xb = (unsigned short*)d_ws;
    unsigned short* wt = (unsigned short*)((char*)d_ws +
                          (size_t)M_DIM * K_DIM * sizeof(unsigned short));

    convert_x_kernel<<<2048, 256, 0, stream>>>(x, xb, M_DIM * K_DIM / 8);

    dim3 tgrid(N_DIM / 64, K_DIM / 64);
    transpose_convert_w<<<tgrid, 256, 0, stream>>>(w, wt);

    dim3 ggrid((M_DIM / BM) * (N_DIM / BN));
    gemm_bf16<<<ggrid, 512, 0, stream>>>(xb, wt, bias, out);
}